// Round 2
// baseline (677.050 us; speedup 1.0000x reference)
//
#include <hip/hip_runtime.h>
#include <hip/hip_bf16.h>
#include <stdint.h>

// PLE layer: T=3 tasks, B=16384 rows, I=1024, O=512, 4 shared + 2 task experts, 6 gates.
// Plan: bf16 MFMA for the 10 expert GEMMs; f32 gates; fused per-task combine.

#define TTASKS 3
#define BROWS  16384
#define KDIM   1024
#define ODIM   512
#define NGATE  6

typedef __attribute__((ext_vector_type(8))) __bf16 bf16x8;
typedef __attribute__((ext_vector_type(4))) float  f32x4;

// ---------------- ws layout ----------------
// xb    [3][16384][1024] bf16 : 100,663,296 B
// wT    [10][512][1024]  bf16 :  10,485,760 B   (4 shared then t0e0,t0e1,t1e0,t1e1,t2e0,t2e1)
// gates [3][16384][6]    f32  :   1,179,648 B
// shOut [4][16384][512]  bf16 :  67,108,864 B
// total 179,437,568 B (~171 MiB) -- assumes ws_size is at least this.
#define XB_OFF 0
#define WT_OFF 100663296UL
#define GT_OFF 111149056UL
#define SH_OFF 112328704UL

// ---------------- cvt inputs f32 -> bf16 ----------------
__global__ __launch_bounds__(256) void cvt_inputs(const float* __restrict__ x,
                                                  __bf16* __restrict__ xb) {
  size_t i = ((size_t)blockIdx.x * 256 + threadIdx.x) * 8;
  const float4* p = (const float4*)(x + i);
  float4 a = p[0], b = p[1];
  bf16x8 o = { (__bf16)a.x, (__bf16)a.y, (__bf16)a.z, (__bf16)a.w,
               (__bf16)b.x, (__bf16)b.y, (__bf16)b.z, (__bf16)b.w };
  *(bf16x8*)(xb + i) = o;
}

// ---------------- cvt + transpose weights: W[k][o] f32 -> wT[o][k] bf16 ----------------
__global__ __launch_bounds__(256) void cvt_weights(const float* __restrict__ shW,
                                                   const float* __restrict__ tkW,
                                                   __bf16* __restrict__ wT) {
  int s = blockIdx.z;
  const float* src = (s < 4) ? (shW + (size_t)s * KDIM * ODIM)
                             : (tkW + (size_t)(s - 4) * KDIM * ODIM);
  int o   = blockIdx.x * 64 + (threadIdx.x & 63);
  int sub = threadIdx.x >> 6;
#pragma unroll
  for (int kk = 0; kk < 2; ++kk) {
    int k0 = blockIdx.y * 64 + (sub * 2 + kk) * 8;
    bf16x8 v;
#pragma unroll
    for (int i = 0; i < 8; ++i)
      v[i] = (__bf16)src[(size_t)(k0 + i) * ODIM + o];  // coalesced across lanes (o contiguous)
    *(bf16x8*)(wT + ((size_t)s * ODIM + o) * KDIM + k0) = v;  // 16B store, strided (small data)
  }
}

// ---------------- gates: one wave per (t,b) row; f32 dots + softmax ----------------
__global__ __launch_bounds__(256) void gates_kernel(const float* __restrict__ x,
                                                    const float* __restrict__ gW,
                                                    const float* __restrict__ gb,
                                                    float* __restrict__ gates) {
  int w = blockIdx.x * 4 + (threadIdx.x >> 6);  // row id 0..49151
  int lane = threadIdx.x & 63;
  int t = w >> 14, b = w & (BROWS - 1);
  const float* xr = x + ((size_t)t * BROWS + b) * KDIM;
  const float* gw = gW + (size_t)t * KDIM * NGATE;
  float d[NGATE] = {0.f, 0.f, 0.f, 0.f, 0.f, 0.f};
  for (int i = 0; i < 16; ++i) {
    int k = i * 64 + lane;
    float xv = xr[k];
#pragma unroll
    for (int j = 0; j < NGATE; ++j) d[j] += xv * gw[k * NGATE + j];
  }
#pragma unroll
  for (int j = 0; j < NGATE; ++j) {
#pragma unroll
    for (int off = 32; off > 0; off >>= 1) d[j] += __shfl_xor(d[j], off, 64);
    d[j] += gb[t * NGATE + j];
  }
  float m = d[0];
#pragma unroll
  for (int j = 1; j < NGATE; ++j) m = fmaxf(m, d[j]);
  float s = 0.f;
#pragma unroll
  for (int j = 0; j < NGATE; ++j) { d[j] = expf(d[j] - m); s += d[j]; }
  float inv = 1.f / s;
  if (lane < NGATE) {
    float v = d[0];
#pragma unroll
    for (int j = 1; j < NGATE; ++j) v = (lane == j) ? d[j] : v;
    gates[(size_t)w * NGATE + lane] = v * inv;
  }
}

// ---------------- 128x128x(K=1024) bf16 MFMA tile GEMM core ----------------
// A rows: Aptr[r*1024 + k] (r=0..127). B cols: Bptr[n*1024 + k] (n=0..127, = W^T rows).
// acc[m][n] = 16x16 fragment at rows wm*64+m*16, cols wn*64+n*16.
__device__ __forceinline__ void gemm_128x128(const __bf16* __restrict__ Aptr,
                                             const __bf16* __restrict__ Bptr,
                                             __bf16* As, __bf16* Bs,
                                             f32x4 acc[4][4]) {
  const int tid = threadIdx.x;
  const int lane = tid & 63;
  const int wv = tid >> 6;
  const int wm = wv >> 1, wn = wv & 1;
  const int lr = lane & 15, lg = lane >> 4;

  for (int kt = 0; kt < 16; ++kt) {
    const int k0 = kt * 64;
    // stage A and B tiles ([128][64] bf16 each) via async global->LDS, 16B/lane
#pragma unroll
    for (int it = 0; it < 4; ++it) {
      int idx = it * 256 + tid;          // 0..1023
      int r   = idx >> 3;                // row / n index 0..127
      int c8  = (idx & 7) << 3;          // k offset 0..56
      __builtin_amdgcn_global_load_lds(
          (const __attribute__((address_space(1))) void*)(Aptr + (size_t)r * KDIM + k0 + c8),
          (__attribute__((address_space(3))) void*)(As + (it * 256 + wv * 64) * 8), 16, 0, 0);
      __builtin_amdgcn_global_load_lds(
          (const __attribute__((address_space(1))) void*)(Bptr + (size_t)r * KDIM + k0 + c8),
          (__attribute__((address_space(3))) void*)(Bs + (it * 256 + wv * 64) * 8), 16, 0, 0);
    }
    __syncthreads();  // drains vmcnt + lgkmcnt

    const __bf16* aB = As + (wm * 64 + lr) * 64 + lg * 8;
    const __bf16* bB = Bs + (wn * 64 + lr) * 64 + lg * 8;
#pragma unroll
    for (int ks = 0; ks < 2; ++ks) {
      bf16x8 af[4], bf[4];
#pragma unroll
      for (int m = 0; m < 4; ++m) af[m] = *(const bf16x8*)(aB + m * 1024 + ks * 32);
#pragma unroll
      for (int n = 0; n < 4; ++n) bf[n] = *(const bf16x8*)(bB + n * 1024 + ks * 32);
#pragma unroll
      for (int m = 0; m < 4; ++m)
#pragma unroll
        for (int n = 0; n < 4; ++n)
          acc[m][n] = __builtin_amdgcn_mfma_f32_16x16x32_bf16(af[m], bf[n], acc[m][n], 0, 0, 0);
    }
    __syncthreads();
  }
}

// ---------------- shared experts: relu(x0 @ W_e + b_e) -> bf16 ----------------
__global__ __launch_bounds__(256, 2) void shared_gemm(const __bf16* __restrict__ xb0,
                                                      const __bf16* __restrict__ wT,
                                                      const float* __restrict__ shb,
                                                      __bf16* __restrict__ shOut) {
  __shared__ __bf16 As[128 * 64], Bs[128 * 64];
  const int e = blockIdx.z;
  const int rowBase = blockIdx.x * 128, colBase = blockIdx.y * 128;
  const int tid = threadIdx.x, lane = tid & 63, wv = tid >> 6;
  const int wm = wv >> 1, wn = wv & 1, lr = lane & 15, lg = lane >> 4;

  f32x4 acc[4][4];
  f32x4 z = {0.f, 0.f, 0.f, 0.f};
#pragma unroll
  for (int m = 0; m < 4; ++m)
#pragma unroll
    for (int n = 0; n < 4; ++n) acc[m][n] = z;

  gemm_128x128(xb0 + (size_t)rowBase * KDIM,
               wT + ((size_t)e * ODIM + colBase) * KDIM, As, Bs, acc);

#pragma unroll
  for (int n = 0; n < 4; ++n) {
    int col = colBase + wn * 64 + n * 16 + lr;
    float bias = shb[e * ODIM + col];
#pragma unroll
    for (int m = 0; m < 4; ++m)
#pragma unroll
      for (int r = 0; r < 4; ++r) {
        int row = rowBase + wm * 64 + m * 16 + lg * 4 + r;
        float v = fmaxf(acc[m][n][r] + bias, 0.f);
        shOut[((size_t)e * BROWS + row) * ODIM + col] = (__bf16)v;
      }
  }
}

// ---------------- per-task: 2 task-expert GEMMs + gated combine with shared ----------------
__global__ __launch_bounds__(256, 2) void task_gemm(const __bf16* __restrict__ xb,
                                                    const __bf16* __restrict__ wT,
                                                    const float* __restrict__ tkb,
                                                    const float* __restrict__ gates,
                                                    const __bf16* __restrict__ shOut,
                                                    float* __restrict__ out) {
  __shared__ __bf16 As[128 * 64], Bs[128 * 64];
  const int t = blockIdx.z;
  const int rowBase = blockIdx.x * 128, colBase = blockIdx.y * 128;
  const int tid = threadIdx.x, lane = tid & 63, wv = tid >> 6;
  const int wm = wv >> 1, wn = wv & 1, lr = lane & 15, lg = lane >> 4;

  float outv[4][4][4];

  // 1) shared-expert contributions (bf16 shOut from previous kernel, gates f32)
#pragma unroll
  for (int m = 0; m < 4; ++m)
#pragma unroll
    for (int r = 0; r < 4; ++r) {
      int row = rowBase + wm * 64 + m * 16 + lg * 4 + r;
      const float* gp = gates + ((size_t)t * BROWS + row) * NGATE;
      float g0 = gp[0], g1 = gp[1], g2 = gp[2], g3 = gp[3];
#pragma unroll
      for (int n = 0; n < 4; ++n) {
        int col = colBase + wn * 64 + n * 16 + lr;
        size_t rc = (size_t)row * ODIM + col;
        float s = g0 * (float)shOut[rc]
                + g1 * (float)shOut[(size_t)BROWS * ODIM + rc]
                + g2 * (float)shOut[2 * (size_t)BROWS * ODIM + rc]
                + g3 * (float)shOut[3 * (size_t)BROWS * ODIM + rc];
        outv[m][n][r] = s;
      }
    }

  // 2) the two task experts, fused
#pragma unroll 1
  for (int j = 0; j < 2; ++j) {
    f32x4 acc[4][4];
    f32x4 z = {0.f, 0.f, 0.f, 0.f};
#pragma unroll
    for (int m = 0; m < 4; ++m)
#pragma unroll
      for (int n = 0; n < 4; ++n) acc[m][n] = z;

    gemm_128x128(xb + ((size_t)t * BROWS + rowBase) * KDIM,
                 wT + ((size_t)(4 + t * 2 + j) * ODIM + colBase) * KDIM, As, Bs, acc);

#pragma unroll
    for (int n = 0; n < 4; ++n) {
      int col = colBase + wn * 64 + n * 16 + lr;
      float bias = tkb[(t * 2 + j) * ODIM + col];
#pragma unroll
      for (int m = 0; m < 4; ++m)
#pragma unroll
        for (int r = 0; r < 4; ++r) {
          int row = rowBase + wm * 64 + m * 16 + lg * 4 + r;
          float g = gates[((size_t)t * BROWS + row) * NGATE + 4 + j];
          outv[m][n][r] += g * fmaxf(acc[m][n][r] + bias, 0.f);
        }
    }
  }

  // 3) store final output
#pragma unroll
  for (int n = 0; n < 4; ++n) {
    int col = colBase + wn * 64 + n * 16 + lr;
#pragma unroll
    for (int m = 0; m < 4; ++m)
#pragma unroll
      for (int r = 0; r < 4; ++r) {
        int row = rowBase + wm * 64 + m * 16 + lg * 4 + r;
        out[((size_t)t * BROWS + row) * ODIM + col] = outv[m][n][r];
      }
  }
}

extern "C" void kernel_launch(void* const* d_in, const int* in_sizes, int n_in,
                              void* d_out, int out_size, void* d_ws, size_t ws_size,
                              hipStream_t stream) {
  const float* x   = (const float*)d_in[0];  // [3][16384][1024]
  const float* shW = (const float*)d_in[1];  // [4][1024][512]
  const float* shb = (const float*)d_in[2];  // [4][512]
  const float* tkW = (const float*)d_in[3];  // [3][2][1024][512]
  const float* tkb = (const float*)d_in[4];  // [3][2][512]
  const float* gW  = (const float*)d_in[5];  // [3][1024][6]
  const float* gb  = (const float*)d_in[6];  // [3][6]
  float* out = (float*)d_out;                // [3][16384][512]
  (void)in_sizes; (void)n_in; (void)out_size; (void)ws_size;

  char* ws = (char*)d_ws;
  __bf16* xb    = (__bf16*)(ws + XB_OFF);
  __bf16* wT    = (__bf16*)(ws + WT_OFF);
  float*  gates = (float*) (ws + GT_OFF);
  __bf16* shOut = (__bf16*)(ws + SH_OFF);

  // 1) casts + gates (independent)
  cvt_inputs <<<dim3(24576), 256, 0, stream>>>(x, xb);
  cvt_weights<<<dim3(8, 16, 10), 256, 0, stream>>>(shW, tkW, wT);
  gates_kernel<<<dim3((TTASKS * BROWS) / 4), 256, 0, stream>>>(x, gW, gb, gates);

  // 2) shared experts -> bf16 intermediate
  shared_gemm<<<dim3(BROWS / 128, ODIM / 128, 4), 256, 0, stream>>>(xb, wT, shb, shOut);

  // 3) per-task fused: task experts + gated combine
  task_gemm<<<dim3(BROWS / 128, ODIM / 128, TTASKS), 256, 0, stream>>>(xb, wT, tkb, gates,
                                                                       shOut, out);
}